// Round 7
// baseline (288.445 us; speedup 1.0000x reference)
//
#include <hip/hip_runtime.h>

// Workspace float offsets
#define F_XM    0u          // bf16 xm[8][4096][256]      -> 4,194,304 f
#define F_XG    4194304u    // bf16 xg[8][2][4096][256]   -> 8,388,608 f
#define F_Y     4194304u    // bf16 y[8][2][4096][128] aliases xg (dead after k_g)
#define F_TH    12582912u   // bf16 theta[8][4096][128]   -> 2,097,152 f
#define F_PHIB  14680064u   // bf16 phi[8][1024][128]     ->   524,288 f
#define F_GB    15204352u   // bf16 g[8][256][1024]       -> 1,048,576 f
// total 16,252,928 floats = 65.0 MB

typedef __attribute__((ext_vector_type(4))) float f32x4;
typedef __attribute__((ext_vector_type(8))) short bf16x8;

__device__ __forceinline__ unsigned short f2bf(float f) {
  union { unsigned int i; float f; } x; x.f = f;
  unsigned int r = x.i + 0x7fffu + ((x.i >> 16) & 1u);
  return (unsigned short)(r >> 16);
}
__device__ __forceinline__ unsigned int pk2(float a, float b) {
  return (unsigned int)f2bf(a) | ((unsigned int)f2bf(b) << 16);
}

// ---------------------------------------------------------------------------
// Prep: x f32 [b][512][4096] -> bf16 xm[b][n][256] (mean over group pair) and
// xg[b][gr][n][256] (K-contiguous layouts for the MFMA GEMMs).
// ---------------------------------------------------------------------------
__global__ __launch_bounds__(256)
void k_prep(const float* __restrict__ x, float* __restrict__ ws) {
  const int nt = blockIdx.x, ct = blockIdx.y, b = blockIdx.z;
  const int n0 = nt * 256, c0 = ct * 64;
  const int tid = threadIdx.x;
  __shared__ uint4 ldsb[4096];               // 64 KB: f32 [64 c][1024B] swz
  char* lds = (char*)ldsb;
  {
    const int c = tid >> 2;
    const int nch = (tid & 3) * 64;
    const float* src = x + ((size_t)(b * 512 + c0 + c)) * 4096 + n0 + nch;
    char* row = lds + c * 1024;
    const int sw = (c & 7) << 4;
    const int bb = nch * 4;
#pragma unroll
    for (int k = 0; k < 16; ++k)
      *(uint4*)(row + ((bb + 16 * k) ^ sw)) = ((const uint4*)src)[k];
  }
  __syncthreads();
  {
    const int n = tid;
    unsigned int u0[16], u1[16], um[16];
#pragma unroll
    for (int jc = 0; jc < 4; ++jc) {
      float v[16];
#pragma unroll
      for (int cc = 0; cc < 16; ++cc) {
        const int c = 16 * jc + cc;
        v[cc] = *(const float*)(lds + c * 1024 + ((n * 4) ^ ((c & 7) << 4)));
      }
#pragma unroll
      for (int s = 0; s < 4; ++s) {
        u0[4 * jc + s] = pk2(v[4 * s], v[4 * s + 2]);
        u1[4 * jc + s] = pk2(v[4 * s + 1], v[4 * s + 3]);
        um[4 * jc + s] = pk2(0.5f * (v[4 * s] + v[4 * s + 1]),
                             0.5f * (v[4 * s + 2] + v[4 * s + 3]));
      }
    }
    unsigned short* xm = (unsigned short*)(ws + F_XM);
    unsigned short* xg = (unsigned short*)(ws + F_XG);
    uint4* d0 = (uint4*)(xg + (((size_t)(b * 2 + 0) * 4096) + n0 + n) * 256 + (c0 >> 1));
    uint4* d1 = (uint4*)(xg + (((size_t)(b * 2 + 1) * 4096) + n0 + n) * 256 + (c0 >> 1));
    uint4* dm = (uint4*)(xm + ((size_t)(b * 4096) + n0 + n) * 256 + (c0 >> 1));
#pragma unroll
    for (int s = 0; s < 4; ++s) {
      d0[s] = make_uint4(u0[4 * s], u0[4 * s + 1], u0[4 * s + 2], u0[4 * s + 3]);
      d1[s] = make_uint4(u1[4 * s], u1[4 * s + 1], u1[4 * s + 2], u1[4 * s + 3]);
      dm[s] = make_uint4(um[4 * s], um[4 * s + 1], um[4 * s + 2], um[4 * s + 3]);
    }
  }
}

// ---------------------------------------------------------------------------
// theta & phi projections from xm (K=256). Out tile 128 o x 128 n, 4 waves.
// ot=0: theta[b][n][o] bf16 (LDS transpose). ot=1: pooled phiB[b][m][o] bf16.
// ---------------------------------------------------------------------------
__global__ __launch_bounds__(256)
void k_proj_mfma(const float* __restrict__ tw, const float* __restrict__ tb,
                 const float* __restrict__ pw, const float* __restrict__ pb,
                 float* __restrict__ ws) {
  const int nt = blockIdx.x, ot = blockIdx.y, b = blockIdx.z;
  const int n0 = nt * 128;
  const int tid = threadIdx.x;
  const int w = tid >> 6, lane = tid & 63, q = lane >> 4, col = lane & 15;
  const float* W = ot ? pw : tw;
  const float* bias = ot ? pb : tb;
  const unsigned short* xm = (const unsigned short*)(ws + F_XM);

  __shared__ uint4 ldsb[4096];               // 64 KB
  char* Ws = (char*)ldsb;                    // [128 o][128B] swz
  char* Xs = (char*)ldsb + 16384;            // [128 n][128B] swz

  f32x4 acc[2][8];
#pragma unroll
  for (int h = 0; h < 2; ++h)
#pragma unroll
    for (int j = 0; j < 8; ++j) acc[h][j] = (f32x4){0.f, 0.f, 0.f, 0.f};

  const int ro = tid >> 1, haf = tid & 1;
  for (int ks = 0; ks < 4; ++ks) {
    __syncthreads();
    {
      const float* src = W + (size_t)ro * 256 + ks * 64 + haf * 32;
      char* row = Ws + ro * 128;
      const int sw = (ro & 7) << 4;
#pragma unroll
      for (int jj = 0; jj < 4; ++jj) {
        float4 a = ((const float4*)src)[2 * jj];
        float4 c4 = ((const float4*)src)[2 * jj + 1];
        uint4 pk;
        pk.x = pk2(a.x, a.y);  pk.y = pk2(a.z, a.w);
        pk.z = pk2(c4.x, c4.y); pk.w = pk2(c4.z, c4.w);
        *(uint4*)(row + ((haf * 64 + 16 * jj) ^ sw)) = pk;
      }
    }
    {
      const unsigned short* src = xm + ((size_t)(b * 4096) + n0 + ro) * 256 + ks * 64 + haf * 32;
      char* row = Xs + ro * 128;
      const int sw = (ro & 7) << 4;
#pragma unroll
      for (int jj = 0; jj < 4; ++jj)
        *(uint4*)(row + ((haf * 64 + 16 * jj) ^ sw)) = ((const uint4*)src)[jj];
    }
    __syncthreads();
#pragma unroll
    for (int c = 0; c < 2; ++c) {
      bf16x8 af[2], bfr[8];
#pragma unroll
      for (int h = 0; h < 2; ++h) {
        const int r = 32 * w + 16 * h + col;
        af[h] = *(const bf16x8*)(Ws + r * 128 + ((64 * c + 16 * q) ^ ((r & 7) << 4)));
      }
#pragma unroll
      for (int j = 0; j < 8; ++j) {
        const int r = 16 * j + col;
        bfr[j] = *(const bf16x8*)(Xs + r * 128 + ((64 * c + 16 * q) ^ ((r & 7) << 4)));
      }
#pragma unroll
      for (int h = 0; h < 2; ++h)
#pragma unroll
        for (int j = 0; j < 8; ++j)
          acc[h][j] = __builtin_amdgcn_mfma_f32_16x16x32_bf16(af[h], bfr[j], acc[h][j], 0, 0, 0);
    }
  }

  float bs[2][4];
#pragma unroll
  for (int h = 0; h < 2; ++h) {
    const int o0 = 32 * w + 16 * h + 4 * q;
#pragma unroll
    for (int r = 0; r < 4; ++r) bs[h][r] = bias[o0 + r];
  }

  if (ot == 0) {
    char* trb = (char*)ldsb + 32768;         // [128 n][256B] swz, fresh region
#pragma unroll
    for (int h = 0; h < 2; ++h) {
      const int o0 = 32 * w + 16 * h + 4 * q;
#pragma unroll
      for (int j = 0; j < 8; ++j) {
        const int n = 16 * j + col;
        uint2 pkk = make_uint2(pk2(acc[h][j][0] + bs[h][0], acc[h][j][1] + bs[h][1]),
                               pk2(acc[h][j][2] + bs[h][2], acc[h][j][3] + bs[h][3]));
        *(uint2*)(trb + n * 256 + ((2 * o0) ^ ((n & 7) << 4))) = pkk;
      }
    }
    __syncthreads();
    {
      const int n = tid >> 1, h2 = tid & 1;
      unsigned short* dst = (unsigned short*)(ws + F_TH) + ((size_t)(b * 4096) + n0 + n) * 128 + h2 * 64;
      const char* row = trb + n * 256;
      const int sw = (n & 7) << 4;
#pragma unroll
      for (int k = 0; k < 8; ++k)
        ((uint4*)dst)[k] = *(const uint4*)(row + ((128 * h2 + 16 * k) ^ sw));
    }
  } else {
    const int mb = (nt >> 3) * 256 + (nt & 7) * 32;
    unsigned short* phiB = (unsigned short*)(ws + F_PHIB);
#pragma unroll
    for (int h = 0; h < 2; ++h) {
      const int o0 = 32 * w + 16 * h + 4 * q;
#pragma unroll
      for (int jj = 0; jj < 4; ++jj) {
        const int j = (jj >> 1) * 4 + (jj & 1);   // {0,1,4,5}
        f32x4 pm;
#pragma unroll
        for (int r = 0; r < 4; ++r)
          pm[r] = fmaxf(acc[h][j][r], acc[h][j + 2][r]);
#pragma unroll
        for (int r = 0; r < 4; ++r)
          pm[r] = fmaxf(pm[r], __shfl_xor(pm[r], 1));
        if ((col & 1) == 0) {
          const int vp = 8 * (j & 1) + (col >> 1);
          const int m = mb + 16 * (j >> 2) + vp;
          uint2 pkk = make_uint2(pk2(pm[0] + bs[h][0], pm[1] + bs[h][1]),
                                 pk2(pm[2] + bs[h][2], pm[3] + bs[h][3]));
          *(uint2*)(phiB + ((size_t)(b * 1024) + m) * 128 + o0) = pkk;
        }
      }
    }
  }
}

// ---------------------------------------------------------------------------
// g projection from xg (per group, K=256), fused pool -> gB[b][d=2o+gr][m].
// ---------------------------------------------------------------------------
__global__ __launch_bounds__(256)
void k_g_mfma(const float* __restrict__ gw, const float* __restrict__ gb,
              float* __restrict__ ws) {
  const int nt = blockIdx.x, gr = blockIdx.y, b = blockIdx.z;
  const int n0 = nt * 128;
  const int tid = threadIdx.x;
  const int w = tid >> 6, lane = tid & 63, q = lane >> 4, col = lane & 15;
  const unsigned short* xg = (const unsigned short*)(ws + F_XG);

  __shared__ uint4 ldsb[4096];
  char* Ws = (char*)ldsb;
  char* Xs = (char*)ldsb + 16384;

  f32x4 acc[2][8];
#pragma unroll
  for (int h = 0; h < 2; ++h)
#pragma unroll
    for (int j = 0; j < 8; ++j) acc[h][j] = (f32x4){0.f, 0.f, 0.f, 0.f};

  const int ro = tid >> 1, haf = tid & 1;
  for (int ks = 0; ks < 4; ++ks) {
    __syncthreads();
    {
      const float* src = gw + (size_t)ro * 256 + ks * 64 + haf * 32;
      char* row = Ws + ro * 128;
      const int sw = (ro & 7) << 4;
#pragma unroll
      for (int jj = 0; jj < 4; ++jj) {
        float4 a = ((const float4*)src)[2 * jj];
        float4 c4 = ((const float4*)src)[2 * jj + 1];
        uint4 pk;
        pk.x = pk2(a.x, a.y);  pk.y = pk2(a.z, a.w);
        pk.z = pk2(c4.x, c4.y); pk.w = pk2(c4.z, c4.w);
        *(uint4*)(row + ((haf * 64 + 16 * jj) ^ sw)) = pk;
      }
    }
    {
      const unsigned short* src = xg + (((size_t)(b * 2 + gr)) * 4096 + n0 + ro) * 256 + ks * 64 + haf * 32;
      char* row = Xs + ro * 128;
      const int sw = (ro & 7) << 4;
#pragma unroll
      for (int jj = 0; jj < 4; ++jj)
        *(uint4*)(row + ((haf * 64 + 16 * jj) ^ sw)) = ((const uint4*)src)[jj];
    }
    __syncthreads();
#pragma unroll
    for (int c = 0; c < 2; ++c) {
      bf16x8 af[2], bfr[8];
#pragma unroll
      for (int h = 0; h < 2; ++h) {
        const int r = 32 * w + 16 * h + col;
        af[h] = *(const bf16x8*)(Ws + r * 128 + ((64 * c + 16 * q) ^ ((r & 7) << 4)));
      }
#pragma unroll
      for (int j = 0; j < 8; ++j) {
        const int r = 16 * j + col;
        bfr[j] = *(const bf16x8*)(Xs + r * 128 + ((64 * c + 16 * q) ^ ((r & 7) << 4)));
      }
#pragma unroll
      for (int h = 0; h < 2; ++h)
#pragma unroll
        for (int j = 0; j < 8; ++j)
          acc[h][j] = __builtin_amdgcn_mfma_f32_16x16x32_bf16(af[h], bfr[j], acc[h][j], 0, 0, 0);
    }
  }

  const int mb = (nt >> 3) * 256 + (nt & 7) * 32;
  char* pt = (char*)ldsb + 32768;            // [128 o][80B], fresh region
#pragma unroll
  for (int h = 0; h < 2; ++h) {
    const int o0 = 32 * w + 16 * h + 4 * q;
#pragma unroll
    for (int jj = 0; jj < 4; ++jj) {
      const int j = (jj >> 1) * 4 + (jj & 1);
      f32x4 pm;
#pragma unroll
      for (int r = 0; r < 4; ++r)
        pm[r] = fmaxf(acc[h][j][r], acc[h][j + 2][r]);
#pragma unroll
      for (int r = 0; r < 4; ++r)
        pm[r] = fmaxf(pm[r], __shfl_xor(pm[r], 1));
      if ((col & 1) == 0) {
        const int ml = 16 * (j >> 2) + 8 * (j & 1) + (col >> 1);
#pragma unroll
        for (int r = 0; r < 4; ++r)
          *(unsigned short*)(pt + (o0 + r) * 80 + ml * 2) = f2bf(pm[r] + gb[o0 + r]);
      }
    }
  }
  __syncthreads();
  if (tid < 128) {
    const int o = tid;
    const char* row = pt + o * 80;
    unsigned short* dst = (unsigned short*)(ws + F_GB) + ((size_t)(b * 256) + 2 * o + gr) * 1024 + mb;
#pragma unroll
    for (int k = 0; k < 4; ++k)
      ((uint4*)dst)[k] = *(const uint4*)(row + 16 * k);
  }
}

// ---------------------------------------------------------------------------
// MFMA flash attention v4: barrier-free main loop. K and V fragments are
// loaded DIRECTLY from global (per-XCD L2-resident: K 256KB + V 512KB) —
// both are K-contiguous for the MFMA A-operand, so no LDS staging at all.
// 4 waves x 16 rows per block; wave-private LDS only for the P repack.
// ---------------------------------------------------------------------------
__global__ __launch_bounds__(256)
void k_attn_mfma(float* __restrict__ ws) {
  const int b = blockIdx.x;          // 8 batches -> 8 XCDs (round-robin)
  const int n0 = blockIdx.y * 64;
  const int tid = threadIdx.x;
  const int w = tid >> 6;
  const int lane = tid & 63;
  const int q = lane >> 4;
  const int col = lane & 15;
  const int ksw = (col & 7) << 4;

  __shared__ char lds[40960];        // [0,32K): epilogue buf; [32K,40K): P
  char* plw = lds + 32768 + w * 2048;

  const unsigned short* thetaB = (const unsigned short*)(ws + F_TH);
  const unsigned short* phiB   = (const unsigned short*)(ws + F_PHIB);
  const unsigned short* gB     = (const unsigned short*)(ws + F_GB);
  unsigned short* yB = (unsigned short*)(ws + F_Y);

  // per-lane global bases (element units)
  const unsigned short* kb = phiB + ((size_t)(b * 1024 + col)) * 128 + 8 * q;
  const unsigned short* vb = gB + ((size_t)(b * 256 + col)) * 1024 + 8 * q;

  bf16x8 qf[4];
  {
    const unsigned short* qp = thetaB + ((size_t)(b * 4096 + n0 + 16 * w + col)) * 128 + 8 * q;
#pragma unroll
    for (int c = 0; c < 4; ++c) qf[c] = *(const bf16x8*)(qp + 32 * c);
  }

  f32x4 ot[16];
#pragma unroll
  for (int t = 0; t < 16; ++t) ot[t] = (f32x4){0.f, 0.f, 0.f, 0.f};
  float mrun = -1e30f, lsum = 0.f;

  for (int mt = 0; mt < 16; ++mt) {
    const int m0 = mt * 64;

    // S^T = K . Q^T  — kf direct from L2: K[m0+16s+col][32c+8q..+7]
    f32x4 st[4];
#pragma unroll
    for (int s = 0; s < 4; ++s) st[s] = (f32x4){0.f, 0.f, 0.f, 0.f};
    bf16x8 kf[4][4];
#pragma unroll
    for (int c = 0; c < 4; ++c)
#pragma unroll
      for (int s = 0; s < 4; ++s)
        kf[c][s] = *(const bf16x8*)(kb + (size_t)(m0 + 16 * s) * 128 + 32 * c);
    __builtin_amdgcn_s_setprio(1);
#pragma unroll
    for (int c = 0; c < 4; ++c)
#pragma unroll
      for (int s = 0; s < 4; ++s)
        st[s] = __builtin_amdgcn_mfma_f32_16x16x32_bf16(kf[c][s], qf[c], st[s], 0, 0, 0);
    __builtin_amdgcn_s_setprio(0);

    // online softmax with defer-max (threshold 8)
    float pmax = -1e30f;
#pragma unroll
    for (int s = 0; s < 4; ++s)
#pragma unroll
      for (int r = 0; r < 4; ++r) pmax = fmaxf(pmax, st[s][r]);
    pmax = fmaxf(pmax, __shfl_xor(pmax, 16));
    pmax = fmaxf(pmax, __shfl_xor(pmax, 32));
    if (!__all(pmax - mrun <= 8.f)) {
      const float mnew = fmaxf(mrun, pmax);
      const float scl = __expf(mrun - mnew);
      mrun = mnew;
      lsum *= scl;
#pragma unroll
      for (int t = 0; t < 16; ++t) {
        ot[t][0] *= scl; ot[t][1] *= scl; ot[t][2] *= scl; ot[t][3] *= scl;
      }
    }
    float rsum = 0.f;
#pragma unroll
    for (int s = 0; s < 4; ++s)
#pragma unroll
      for (int r = 0; r < 4; ++r) {
        st[s][r] = __expf(st[s][r] - mrun);   // p in-place
        rsum += st[s][r];
      }
    rsum += __shfl_xor(rsum, 16);
    rsum += __shfl_xor(rsum, 32);
    lsum += rsum;

    // P -> bf16 -> wave-private LDS -> B-fragments (no barrier needed)
    char* prow = plw + col * 128;
#pragma unroll
    for (int s = 0; s < 4; ++s)
#pragma unroll
      for (int h = 0; h < 2; ++h)
        *(unsigned int*)(prow + ((32 * s + 8 * q + 4 * h) ^ ksw)) =
            pk2(st[s][2 * h], st[s][2 * h + 1]);
    bf16x8 pf[2];
#pragma unroll
    for (int c = 0; c < 2; ++c)
      pf[c] = *(const bf16x8*)(prow + ((64 * c + 16 * q) ^ ksw));

    // O^T += V^T . P^T — vf direct from L2: V^T[16t+col][m0+32c+8q..+7]
    __builtin_amdgcn_s_setprio(1);
#pragma unroll
    for (int c = 0; c < 2; ++c)
#pragma unroll
      for (int t = 0; t < 16; ++t) {
        const bf16x8 vf = *(const bf16x8*)(vb + (size_t)(16 * t) * 1024 + m0 + 32 * c);
        ot[t] = __builtin_amdgcn_mfma_f32_16x16x32_bf16(vf, pf[c], ot[t], 0, 0, 0);
      }
    __builtin_amdgcn_s_setprio(0);
  }

  // epilogue: y[b][gr][n][i] bf16. d = 16t+4q+r -> gr=r&1, i = 8t+2q+(r>>1)
  const float inv = 1.f / lsum;
  char* yt = lds;                    // [128 rows (gr*64+nl)][256B] swz
  const int nl = 16 * w + col;
  const int swn = (nl & 7) << 4;
#pragma unroll
  for (int t = 0; t < 16; ++t) {
    const unsigned int w0 = pk2(ot[t][0] * inv, ot[t][2] * inv);
    const unsigned int w1 = pk2(ot[t][1] * inv, ot[t][3] * inv);
    const int bo = 16 * t + 4 * q;
    *(unsigned int*)(yt + nl * 256 + (bo ^ swn)) = w0;
    *(unsigned int*)(yt + (64 + nl) * 256 + (bo ^ swn)) = w1;
  }
  __syncthreads();
  {
    const int row = tid >> 1, h2 = tid & 1;
    const int gr = row >> 6, n = row & 63;
    unsigned short* dst = yB + (((size_t)(b * 2 + gr)) * 4096 + n0 + n) * 128 + h2 * 64;
    const char* srow = yt + row * 256;
    const int sw = (n & 7) << 4;
#pragma unroll
    for (int k = 0; k < 8; ++k)
      ((uint4*)dst)[k] = *(const uint4*)(srow + ((128 * h2 + 16 * k) ^ sw));
  }
}

// ---------------------------------------------------------------------------
// Final W conv (MFMA, K=128 per group) + bias + residual.
// ---------------------------------------------------------------------------
__global__ __launch_bounds__(256)
void k_final_mfma(const float* __restrict__ x,
                  const float* __restrict__ Ww, const float* __restrict__ Wb,
                  const float* __restrict__ ws, float* __restrict__ out) {
  const int nt = blockIdx.x, gq = blockIdx.y, b = blockIdx.z;
  const int gr = gq & 1, ob = (gq >> 1) * 128;
  const int n0 = nt * 128;
  const int tid = threadIdx.x;
  const int w = tid >> 6, lane = tid & 63, q = lane >> 4, col = lane & 15;
  const unsigned short* yb = (const unsigned short*)(ws + F_Y);

  __shared__ uint4 ldsb[4096];
  char* As = (char*)ldsb;
  char* Bs = (char*)ldsb + 16384;

  f32x4 acc[2][8];
#pragma unroll
  for (int h = 0; h < 2; ++h)
#pragma unroll
    for (int j = 0; j < 8; ++j) acc[h][j] = (f32x4){0.f, 0.f, 0.f, 0.f};

  const int ro = tid >> 1, haf = tid & 1;
  for (int ks = 0; ks < 2; ++ks) {
    __syncthreads();
    {
      const float* src = Ww + (size_t)(ob + ro) * 128 + ks * 64 + haf * 32;
      char* row = As + ro * 128;
      const int sw = (ro & 7) << 4;
#pragma unroll
      for (int jj = 0; jj < 4; ++jj) {
        float4 a = ((const float4*)src)[2 * jj];
        float4 c4 = ((const float4*)src)[2 * jj + 1];
        uint4 pk;
        pk.x = pk2(a.x, a.y);  pk.y = pk2(a.z, a.w);
        pk.z = pk2(c4.x, c4.y); pk.w = pk2(c4.z, c4.w);
        *(uint4*)(row + ((haf * 64 + 16 * jj) ^ sw)) = pk;
      }
    }
    {
      const unsigned short* src = yb + (((size_t)(b * 2 + gr)) * 4096 + n0 + ro) * 128 + ks * 64 + haf * 32;
      char* row = Bs + ro * 128;
      const int sw = (ro & 7) << 4;
#pragma unroll
      for (int jj = 0; jj < 4; ++jj)
        *(uint4*)(row + ((haf * 64 + 16 * jj) ^ sw)) = ((const uint4*)src)[jj];
    }
    __syncthreads();
#pragma unroll
    for (int c = 0; c < 2; ++c) {
      bf16x8 af[2], bfr[8];
#pragma unroll
      for (int h = 0; h < 2; ++h) {
        const int r = 32 * w + 16 * h + col;
        af[h] = *(const bf16x8*)(As + r * 128 + ((64 * c + 16 * q) ^ ((r & 7) << 4)));
      }
#pragma unroll
      for (int j = 0; j < 8; ++j) {
        const int r = 16 * j + col;
        bfr[j] = *(const bf16x8*)(Bs + r * 128 + ((64 * c + 16 * q) ^ ((r & 7) << 4)));
      }
#pragma unroll
      for (int h = 0; h < 2; ++h)
#pragma unroll
        for (int j = 0; j < 8; ++j)
          acc[h][j] = __builtin_amdgcn_mfma_f32_16x16x32_bf16(af[h], bfr[j], acc[h][j], 0, 0, 0);
    }
  }

  __syncthreads();                           // reuse whole LDS: f32 [128 o][512B]
  char* ft = (char*)ldsb;
#pragma unroll
  for (int h = 0; h < 2; ++h) {
    const int o0 = 32 * w + 16 * h + 4 * q;
#pragma unroll
    for (int j = 0; j < 8; ++j) {
      const int n = 16 * j + col;
#pragma unroll
      for (int r = 0; r < 4; ++r)
        *(float*)(ft + (o0 + r) * 512 + ((n * 4) ^ (((o0 + r) & 7) << 4))) = acc[h][j][r];
    }
  }
  __syncthreads();
  {
    const int o = tid >> 1, h2 = tid & 1;
    const float bsv = Wb[ob + o];
    const int ch = 2 * (ob + o) + gr;
    const size_t base = ((size_t)(b * 512 + ch)) * 4096 + n0 + h2 * 64;
    const char* row = ft + o * 512;
    const int sw = (o & 7) << 4;
#pragma unroll
    for (int k = 0; k < 16; ++k) {
      f32x4 v = *(const f32x4*)(row + ((256 * h2 + 16 * k) ^ sw));
      float4 xv = ((const float4*)(x + base))[k];
      ((float4*)(out + base))[k] = make_float4(v[0] + bsv + xv.x, v[1] + bsv + xv.y,
                                               v[2] + bsv + xv.z, v[3] + bsv + xv.w);
    }
  }
}

extern "C" void kernel_launch(void* const* d_in, const int* in_sizes, int n_in,
                              void* d_out, int out_size, void* d_ws, size_t ws_size,
                              hipStream_t stream) {
  const float* x  = (const float*)d_in[0];
  const float* gw = (const float*)d_in[1];
  const float* gb = (const float*)d_in[2];
  const float* tw = (const float*)d_in[3];
  const float* tb = (const float*)d_in[4];
  const float* pw = (const float*)d_in[5];
  const float* pb = (const float*)d_in[6];
  const float* Ww = (const float*)d_in[7];
  const float* Wb = (const float*)d_in[8];
  float* out = (float*)d_out;
  float* ws  = (float*)d_ws;

  k_prep<<<dim3(16, 8, 8), 256, 0, stream>>>(x, ws);
  k_proj_mfma<<<dim3(32, 2, 8), 256, 0, stream>>>(tw, tb, pw, pb, ws);
  k_g_mfma<<<dim3(32, 2, 8), 256, 0, stream>>>(gw, gb, ws);
  k_attn_mfma<<<dim3(8, 64), 256, 0, stream>>>(ws);
  k_final_mfma<<<dim3(32, 4, 8), 256, 0, stream>>>(x, Ww, Wb, ws, out);
}

// Round 8
// 163.666 us; speedup vs baseline: 1.7624x; 1.7624x over previous
//
#include <hip/hip_runtime.h>

// Workspace float offsets
#define F_XM    0u          // bf16 xm[8][4096][256]      -> 4,194,304 f
#define F_XG    4194304u    // bf16 xg[8][2][4096][256]   -> 8,388,608 f
#define F_Y     4194304u    // bf16 y[8][2][4096][128] aliases xg (dead after k_g)
#define F_TH    12582912u   // bf16 theta[8][4096][128]   -> 2,097,152 f
#define F_PHIB  14680064u   // bf16 phi[8][1024][128]     ->   524,288 f
#define F_GB    15204352u   // bf16 g[8][256][1024]       -> 1,048,576 f
// total 16,252,928 floats = 65.0 MB

typedef __attribute__((ext_vector_type(4))) float f32x4;
typedef __attribute__((ext_vector_type(8))) short bf16x8;

__device__ __forceinline__ unsigned short f2bf(float f) {
  union { unsigned int i; float f; } x; x.f = f;
  unsigned int r = x.i + 0x7fffu + ((x.i >> 16) & 1u);
  return (unsigned short)(r >> 16);
}
__device__ __forceinline__ unsigned int pk2(float a, float b) {
  return (unsigned int)f2bf(a) | ((unsigned int)f2bf(b) << 16);
}
__device__ __forceinline__ void gload_lds16(const void* g, void* l) {
  __builtin_amdgcn_global_load_lds(
      (const __attribute__((address_space(1))) unsigned int*)g,
      (__attribute__((address_space(3))) unsigned int*)l, 16, 0, 0);
}

// ---------------------------------------------------------------------------
// Prep: x f32 [b][512][4096] -> bf16 xm[b][n][256] (mean over group pair) and
// xg[b][gr][n][256] (K-contiguous layouts for the MFMA GEMMs).
// ---------------------------------------------------------------------------
__global__ __launch_bounds__(256)
void k_prep(const float* __restrict__ x, float* __restrict__ ws) {
  const int nt = blockIdx.x, ct = blockIdx.y, b = blockIdx.z;
  const int n0 = nt * 256, c0 = ct * 64;
  const int tid = threadIdx.x;
  __shared__ uint4 ldsb[4096];               // 64 KB: f32 [64 c][1024B] swz
  char* lds = (char*)ldsb;
  {
    const int c = tid >> 2;
    const int nch = (tid & 3) * 64;
    const float* src = x + ((size_t)(b * 512 + c0 + c)) * 4096 + n0 + nch;
    char* row = lds + c * 1024;
    const int sw = (c & 7) << 4;
    const int bb = nch * 4;
#pragma unroll
    for (int k = 0; k < 16; ++k)
      *(uint4*)(row + ((bb + 16 * k) ^ sw)) = ((const uint4*)src)[k];
  }
  __syncthreads();
  {
    const int n = tid;
    unsigned int u0[16], u1[16], um[16];
#pragma unroll
    for (int jc = 0; jc < 4; ++jc) {
      float v[16];
#pragma unroll
      for (int cc = 0; cc < 16; ++cc) {
        const int c = 16 * jc + cc;
        v[cc] = *(const float*)(lds + c * 1024 + ((n * 4) ^ ((c & 7) << 4)));
      }
#pragma unroll
      for (int s = 0; s < 4; ++s) {
        u0[4 * jc + s] = pk2(v[4 * s], v[4 * s + 2]);
        u1[4 * jc + s] = pk2(v[4 * s + 1], v[4 * s + 3]);
        um[4 * jc + s] = pk2(0.5f * (v[4 * s] + v[4 * s + 1]),
                             0.5f * (v[4 * s + 2] + v[4 * s + 3]));
      }
    }
    unsigned short* xm = (unsigned short*)(ws + F_XM);
    unsigned short* xg = (unsigned short*)(ws + F_XG);
    uint4* d0 = (uint4*)(xg + (((size_t)(b * 2 + 0) * 4096) + n0 + n) * 256 + (c0 >> 1));
    uint4* d1 = (uint4*)(xg + (((size_t)(b * 2 + 1) * 4096) + n0 + n) * 256 + (c0 >> 1));
    uint4* dm = (uint4*)(xm + ((size_t)(b * 4096) + n0 + n) * 256 + (c0 >> 1));
#pragma unroll
    for (int s = 0; s < 4; ++s) {
      d0[s] = make_uint4(u0[4 * s], u0[4 * s + 1], u0[4 * s + 2], u0[4 * s + 3]);
      d1[s] = make_uint4(u1[4 * s], u1[4 * s + 1], u1[4 * s + 2], u1[4 * s + 3]);
      dm[s] = make_uint4(um[4 * s], um[4 * s + 1], um[4 * s + 2], um[4 * s + 3]);
    }
  }
}

// ---------------------------------------------------------------------------
// theta & phi projections from xm (K=256). Out tile 128 o x 128 n, 4 waves.
// ot=0: theta[b][n][o] bf16 (LDS transpose). ot=1: pooled phiB[b][m][o] bf16.
// ---------------------------------------------------------------------------
__global__ __launch_bounds__(256)
void k_proj_mfma(const float* __restrict__ tw, const float* __restrict__ tb,
                 const float* __restrict__ pw, const float* __restrict__ pb,
                 float* __restrict__ ws) {
  const int nt = blockIdx.x, ot = blockIdx.y, b = blockIdx.z;
  const int n0 = nt * 128;
  const int tid = threadIdx.x;
  const int w = tid >> 6, lane = tid & 63, q = lane >> 4, col = lane & 15;
  const float* W = ot ? pw : tw;
  const float* bias = ot ? pb : tb;
  const unsigned short* xm = (const unsigned short*)(ws + F_XM);

  __shared__ uint4 ldsb[4096];               // 64 KB
  char* Ws = (char*)ldsb;                    // [128 o][128B] swz
  char* Xs = (char*)ldsb + 16384;            // [128 n][128B] swz

  f32x4 acc[2][8];
#pragma unroll
  for (int h = 0; h < 2; ++h)
#pragma unroll
    for (int j = 0; j < 8; ++j) acc[h][j] = (f32x4){0.f, 0.f, 0.f, 0.f};

  const int ro = tid >> 1, haf = tid & 1;
  for (int ks = 0; ks < 4; ++ks) {
    __syncthreads();
    {
      const float* src = W + (size_t)ro * 256 + ks * 64 + haf * 32;
      char* row = Ws + ro * 128;
      const int sw = (ro & 7) << 4;
#pragma unroll
      for (int jj = 0; jj < 4; ++jj) {
        float4 a = ((const float4*)src)[2 * jj];
        float4 c4 = ((const float4*)src)[2 * jj + 1];
        uint4 pk;
        pk.x = pk2(a.x, a.y);  pk.y = pk2(a.z, a.w);
        pk.z = pk2(c4.x, c4.y); pk.w = pk2(c4.z, c4.w);
        *(uint4*)(row + ((haf * 64 + 16 * jj) ^ sw)) = pk;
      }
    }
    {
      const unsigned short* src = xm + ((size_t)(b * 4096) + n0 + ro) * 256 + ks * 64 + haf * 32;
      char* row = Xs + ro * 128;
      const int sw = (ro & 7) << 4;
#pragma unroll
      for (int jj = 0; jj < 4; ++jj)
        *(uint4*)(row + ((haf * 64 + 16 * jj) ^ sw)) = ((const uint4*)src)[jj];
    }
    __syncthreads();
#pragma unroll
    for (int c = 0; c < 2; ++c) {
      bf16x8 af[2], bfr[8];
#pragma unroll
      for (int h = 0; h < 2; ++h) {
        const int r = 32 * w + 16 * h + col;
        af[h] = *(const bf16x8*)(Ws + r * 128 + ((64 * c + 16 * q) ^ ((r & 7) << 4)));
      }
#pragma unroll
      for (int j = 0; j < 8; ++j) {
        const int r = 16 * j + col;
        bfr[j] = *(const bf16x8*)(Xs + r * 128 + ((64 * c + 16 * q) ^ ((r & 7) << 4)));
      }
#pragma unroll
      for (int h = 0; h < 2; ++h)
#pragma unroll
        for (int j = 0; j < 8; ++j)
          acc[h][j] = __builtin_amdgcn_mfma_f32_16x16x32_bf16(af[h], bfr[j], acc[h][j], 0, 0, 0);
    }
  }

  float bs[2][4];
#pragma unroll
  for (int h = 0; h < 2; ++h) {
    const int o0 = 32 * w + 16 * h + 4 * q;
#pragma unroll
    for (int r = 0; r < 4; ++r) bs[h][r] = bias[o0 + r];
  }

  if (ot == 0) {
    char* trb = (char*)ldsb + 32768;         // [128 n][256B] swz, fresh region
#pragma unroll
    for (int h = 0; h < 2; ++h) {
      const int o0 = 32 * w + 16 * h + 4 * q;
#pragma unroll
      for (int j = 0; j < 8; ++j) {
        const int n = 16 * j + col;
        uint2 pkk = make_uint2(pk2(acc[h][j][0] + bs[h][0], acc[h][j][1] + bs[h][1]),
                               pk2(acc[h][j][2] + bs[h][2], acc[h][j][3] + bs[h][3]));
        *(uint2*)(trb + n * 256 + ((2 * o0) ^ ((n & 7) << 4))) = pkk;
      }
    }
    __syncthreads();
    {
      const int n = tid >> 1, h2 = tid & 1;
      unsigned short* dst = (unsigned short*)(ws + F_TH) + ((size_t)(b * 4096) + n0 + n) * 128 + h2 * 64;
      const char* row = trb + n * 256;
      const int sw = (n & 7) << 4;
#pragma unroll
      for (int k = 0; k < 8; ++k)
        ((uint4*)dst)[k] = *(const uint4*)(row + ((128 * h2 + 16 * k) ^ sw));
    }
  } else {
    const int mb = (nt >> 3) * 256 + (nt & 7) * 32;
    unsigned short* phiB = (unsigned short*)(ws + F_PHIB);
#pragma unroll
    for (int h = 0; h < 2; ++h) {
      const int o0 = 32 * w + 16 * h + 4 * q;
#pragma unroll
      for (int jj = 0; jj < 4; ++jj) {
        const int j = (jj >> 1) * 4 + (jj & 1);   // {0,1,4,5}
        f32x4 pm;
#pragma unroll
        for (int r = 0; r < 4; ++r)
          pm[r] = fmaxf(acc[h][j][r], acc[h][j + 2][r]);
#pragma unroll
        for (int r = 0; r < 4; ++r)
          pm[r] = fmaxf(pm[r], __shfl_xor(pm[r], 1));
        if ((col & 1) == 0) {
          const int vp = 8 * (j & 1) + (col >> 1);
          const int m = mb + 16 * (j >> 2) + vp;
          uint2 pkk = make_uint2(pk2(pm[0] + bs[h][0], pm[1] + bs[h][1]),
                                 pk2(pm[2] + bs[h][2], pm[3] + bs[h][3]));
          *(uint2*)(phiB + ((size_t)(b * 1024) + m) * 128 + o0) = pkk;
        }
      }
    }
  }
}

// ---------------------------------------------------------------------------
// g projection from xg (per group, K=256), fused pool -> gB[b][d=2o+gr][m].
// ---------------------------------------------------------------------------
__global__ __launch_bounds__(256)
void k_g_mfma(const float* __restrict__ gw, const float* __restrict__ gb,
              float* __restrict__ ws) {
  const int nt = blockIdx.x, gr = blockIdx.y, b = blockIdx.z;
  const int n0 = nt * 128;
  const int tid = threadIdx.x;
  const int w = tid >> 6, lane = tid & 63, q = lane >> 4, col = lane & 15;
  const unsigned short* xg = (const unsigned short*)(ws + F_XG);

  __shared__ uint4 ldsb[4096];
  char* Ws = (char*)ldsb;
  char* Xs = (char*)ldsb + 16384;

  f32x4 acc[2][8];
#pragma unroll
  for (int h = 0; h < 2; ++h)
#pragma unroll
    for (int j = 0; j < 8; ++j) acc[h][j] = (f32x4){0.f, 0.f, 0.f, 0.f};

  const int ro = tid >> 1, haf = tid & 1;
  for (int ks = 0; ks < 4; ++ks) {
    __syncthreads();
    {
      const float* src = gw + (size_t)ro * 256 + ks * 64 + haf * 32;
      char* row = Ws + ro * 128;
      const int sw = (ro & 7) << 4;
#pragma unroll
      for (int jj = 0; jj < 4; ++jj) {
        float4 a = ((const float4*)src)[2 * jj];
        float4 c4 = ((const float4*)src)[2 * jj + 1];
        uint4 pk;
        pk.x = pk2(a.x, a.y);  pk.y = pk2(a.z, a.w);
        pk.z = pk2(c4.x, c4.y); pk.w = pk2(c4.z, c4.w);
        *(uint4*)(row + ((haf * 64 + 16 * jj) ^ sw)) = pk;
      }
    }
    {
      const unsigned short* src = xg + (((size_t)(b * 2 + gr)) * 4096 + n0 + ro) * 256 + ks * 64 + haf * 32;
      char* row = Xs + ro * 128;
      const int sw = (ro & 7) << 4;
#pragma unroll
      for (int jj = 0; jj < 4; ++jj)
        *(uint4*)(row + ((haf * 64 + 16 * jj) ^ sw)) = ((const uint4*)src)[jj];
    }
    __syncthreads();
#pragma unroll
    for (int c = 0; c < 2; ++c) {
      bf16x8 af[2], bfr[8];
#pragma unroll
      for (int h = 0; h < 2; ++h) {
        const int r = 32 * w + 16 * h + col;
        af[h] = *(const bf16x8*)(Ws + r * 128 + ((64 * c + 16 * q) ^ ((r & 7) << 4)));
      }
#pragma unroll
      for (int j = 0; j < 8; ++j) {
        const int r = 16 * j + col;
        bfr[j] = *(const bf16x8*)(Xs + r * 128 + ((64 * c + 16 * q) ^ ((r & 7) << 4)));
      }
#pragma unroll
      for (int h = 0; h < 2; ++h)
#pragma unroll
        for (int j = 0; j < 8; ++j)
          acc[h][j] = __builtin_amdgcn_mfma_f32_16x16x32_bf16(af[h], bfr[j], acc[h][j], 0, 0, 0);
    }
  }

  const int mb = (nt >> 3) * 256 + (nt & 7) * 32;
  char* pt = (char*)ldsb + 32768;            // [128 o][80B], fresh region
#pragma unroll
  for (int h = 0; h < 2; ++h) {
    const int o0 = 32 * w + 16 * h + 4 * q;
#pragma unroll
    for (int jj = 0; jj < 4; ++jj) {
      const int j = (jj >> 1) * 4 + (jj & 1);
      f32x4 pm;
#pragma unroll
      for (int r = 0; r < 4; ++r)
        pm[r] = fmaxf(acc[h][j][r], acc[h][j + 2][r]);
#pragma unroll
      for (int r = 0; r < 4; ++r)
        pm[r] = fmaxf(pm[r], __shfl_xor(pm[r], 1));
      if ((col & 1) == 0) {
        const int ml = 16 * (j >> 2) + 8 * (j & 1) + (col >> 1);
#pragma unroll
        for (int r = 0; r < 4; ++r)
          *(unsigned short*)(pt + (o0 + r) * 80 + ml * 2) = f2bf(pm[r] + gb[o0 + r]);
      }
    }
  }
  __syncthreads();
  if (tid < 128) {
    const int o = tid;
    const char* row = pt + o * 80;
    unsigned short* dst = (unsigned short*)(ws + F_GB) + ((size_t)(b * 256) + 2 * o + gr) * 1024 + mb;
#pragma unroll
    for (int k = 0; k < 4; ++k)
      ((uint4*)dst)[k] = *(const uint4*)(row + 16 * k);
  }
}

// ---------------------------------------------------------------------------
// MFMA flash attention v5: double-buffered async staging via global_load_lds
// (zero VGPR cost, linear LDS dest, pre-swizzled global source), KVBLK=32,
// ONE barrier per iteration. 4 waves x 16 n-rows; LDS 56KB -> 2 blocks/CU.
// ---------------------------------------------------------------------------
#define KVB 32
#define NIT 32
__global__ __launch_bounds__(256)
void k_attn_mfma(float* __restrict__ ws) {
  const int b = blockIdx.x;          // 8 batches -> 8 XCDs (round-robin)
  const int n0 = blockIdx.y * 64;
  const int tid = threadIdx.x;
  const int w = tid >> 6;
  const int lane = tid & 63;
  const int q = lane >> 4;
  const int col = lane & 15;
  const int ksw = (col & 7) << 4;    // K & P swizzle (256/128B rows)
  const int vsw = (col & 3) << 4;    // V swizzle (64B rows)

  __shared__ char lds[57344];
  // kt[2]: 2 x 8KB @ 0      (K tile [32 m][256B], row-swz ((m&7)<<4))
  // vt[2]: 2 x 16KB @ 16384 (V^T tile [256 d][64B], row-swz ((d&3)<<4))
  // pl   : 8KB @ 49152      (per-wave P [16 col][128B])
  char* plw = lds + 49152 + w * 2048;

  const unsigned short* thetaB = (const unsigned short*)(ws + F_TH);
  const char* phiBb = (const char*)((const unsigned short*)(ws + F_PHIB) + (size_t)b * 1024 * 128);
  const char* gBb   = (const char*)((const unsigned short*)(ws + F_GB) + (size_t)b * 256 * 1024);
  unsigned short* yB = (unsigned short*)(ws + F_Y);

  // ---- staging geometry (per-lane swizzled SOURCE, linear LDS dest) ----
  // K: 8 chunks of 1KB; wave w issues chunks w*2+j. Chunk c covers rows 4c..4c+3.
  const int kr0 = lane >> 4;                 // row within chunk
  const int kso = ((lane & 15) * 16);        // linear byte in row
  // V: 16 chunks of 1KB; wave w issues chunks w*4+j. Chunk c covers d=16c..16c+15.
  const int vr0 = lane >> 2;
  const int vso = ((lane & 3) * 16);

  bf16x8 qf[4];
  {
    const unsigned short* qp = thetaB + ((size_t)(b * 4096 + n0 + 16 * w + col)) * 128 + 8 * q;
#pragma unroll
    for (int c = 0; c < 4; ++c) qf[c] = *(const bf16x8*)(qp + 32 * c);
  }

  f32x4 ot[16];
#pragma unroll
  for (int t = 0; t < 16; ++t) ot[t] = (f32x4){0.f, 0.f, 0.f, 0.f};
  float mrun = -1e30f, lsum = 0.f;

  // prologue: stage tile 0 into buffer 0
  {
#pragma unroll
    for (int j = 0; j < 2; ++j) {
      const int c = w * 2 + j;
      const int r = 4 * c + kr0;
      gload_lds16(phiBb + (size_t)r * 256 + (kso ^ ((r & 7) << 4)), lds + c * 1024);
    }
#pragma unroll
    for (int j = 0; j < 4; ++j) {
      const int c = w * 4 + j;
      const int d = 16 * c + vr0;
      gload_lds16(gBb + (size_t)d * 2048 + (vso ^ ((d & 3) << 4)), lds + 16384 + c * 1024);
    }
  }
  __syncthreads();

  int cur = 0;
  for (int mt = 0; mt < NIT; ++mt) {
    char* ktc = lds + cur * 8192;
    char* vtc = lds + 16384 + cur * 16384;
    // stage next tile into the other buffer (async; completes by the barrier)
    if (mt + 1 < NIT) {
      const size_t moff = (size_t)(mt + 1) * KVB;
#pragma unroll
      for (int j = 0; j < 2; ++j) {
        const int c = w * 2 + j;
        const int r = 4 * c + kr0;
        gload_lds16(phiBb + (moff + r) * 256 + (kso ^ ((r & 7) << 4)),
                    lds + (cur ^ 1) * 8192 + c * 1024);
      }
#pragma unroll
      for (int j = 0; j < 4; ++j) {
        const int c = w * 4 + j;
        const int d = 16 * c + vr0;
        gload_lds16(gBb + (size_t)d * 2048 + moff * 2 + (vso ^ ((d & 3) << 4)),
                    lds + 16384 + (cur ^ 1) * 16384 + c * 1024);
      }
    }

    // S^T = K . Q^T  (st[s] covers m-local 16s..16s+15, n = col)
    f32x4 st[2];
#pragma unroll
    for (int s = 0; s < 2; ++s) st[s] = (f32x4){0.f, 0.f, 0.f, 0.f};
    __builtin_amdgcn_s_setprio(1);
#pragma unroll
    for (int c = 0; c < 4; ++c)
#pragma unroll
      for (int s = 0; s < 2; ++s) {
        const bf16x8 kf = *(const bf16x8*)(ktc + (16 * s + col) * 256 +
                                           ((64 * c + 16 * q) ^ ksw));
        st[s] = __builtin_amdgcn_mfma_f32_16x16x32_bf16(kf, qf[c], st[s], 0, 0, 0);
      }
    __builtin_amdgcn_s_setprio(0);

    // online softmax with defer-max (threshold 8)
    float pmax = -1e30f;
#pragma unroll
    for (int s = 0; s < 2; ++s)
#pragma unroll
      for (int r = 0; r < 4; ++r) pmax = fmaxf(pmax, st[s][r]);
    pmax = fmaxf(pmax, __shfl_xor(pmax, 16));
    pmax = fmaxf(pmax, __shfl_xor(pmax, 32));
    if (!__all(pmax - mrun <= 8.f)) {
      const float mnew = fmaxf(mrun, pmax);
      const float scl = __expf(mrun - mnew);
      mrun = mnew;
      lsum *= scl;
#pragma unroll
      for (int t = 0; t < 16; ++t) {
        ot[t][0] *= scl; ot[t][1] *= scl; ot[t][2] *= scl; ot[t][3] *= scl;
      }
    }
    float rsum = 0.f;
#pragma unroll
    for (int s = 0; s < 2; ++s)
#pragma unroll
      for (int r = 0; r < 4; ++r) {
        st[s][r] = __expf(st[s][r] - mrun);
        rsum += st[s][r];
      }
    rsum += __shfl_xor(rsum, 16);
    rsum += __shfl_xor(rsum, 32);
    lsum += rsum;

    // P -> bf16 -> wave-private LDS -> one B-fragment (m=32)
    char* prow = plw + col * 128;
#pragma unroll
    for (int s = 0; s < 2; ++s)
#pragma unroll
      for (int h = 0; h < 2; ++h)
        *(unsigned int*)(prow + ((32 * s + 8 * q + 4 * h) ^ ksw)) =
            pk2(st[s][2 * h], st[s][2 * h + 1]);
    const bf16x8 pf = *(const bf16x8*)(prow + ((16 * q) ^ ksw));

    // O^T += V^T . P^T
    __builtin_amdgcn_s_setprio(1);
#pragma unroll
    for (int t = 0; t < 16; ++t) {
      const int d = 16 * t + col;
      const bf16x8 vf = *(const bf16x8*)(vtc + d * 64 + ((16 * q) ^ vsw));
      ot[t] = __builtin_amdgcn_mfma_f32_16x16x32_bf16(vf, pf, ot[t], 0, 0, 0);
    }
    __builtin_amdgcn_s_setprio(0);

    __syncthreads();   // staged tile complete + all waves done with cur
    cur ^= 1;
  }

  // epilogue: y[b][gr][n][i] bf16. d = 16t+4q+r -> gr=r&1, i = 8t+2q+(r>>1)
  const float inv = 1.f / lsum;
  char* yt = lds;                    // [128 rows (gr*64+nl)][256B] swz
  const int nl = 16 * w + col;
  const int swn = (nl & 7) << 4;
#pragma unroll
  for (int t = 0; t < 16; ++t) {
    const unsigned int w0 = pk2(ot[t][0] * inv, ot[t][2] * inv);
    const unsigned int w1 = pk2(ot[t][1] * inv, ot[t][3] * inv);
    const int bo = 16 * t + 4 * q;
    *(unsigned int*)(yt + nl * 256 + (bo ^ swn)) = w0;
    *(unsigned int*)(yt + (64 + nl) * 256 + (bo ^ swn)) = w1;
  }
  __syncthreads();
  {
    const int row = tid >> 1, h2 = tid & 1;
    const int gr = row >> 6, n = row & 63;
    unsigned short* dst = yB + (((size_t)(b * 2 + gr)) * 4096 + n0 + n) * 128 + h2 * 64;
    const char* srow = yt + row * 256;
    const int sw = (n & 7) << 4;
#pragma unroll
    for (int k = 0; k < 8; ++k)
      ((uint4*)dst)[k] = *(const uint4*)(srow + ((128 * h2 + 16 * k) ^ sw));
  }
}

// ---------------------------------------------------------------------------
// Final W conv (MFMA, K=128 per group) + bias + residual.
// ---------------------------------------------------------------------------
__global__ __launch_bounds__(256)
void k_final_mfma(const float* __restrict__ x,
                  const float* __restrict__ Ww, const float* __restrict__ Wb,
                  const float* __restrict__ ws, float* __restrict__ out) {
  const int nt = blockIdx.x, gq = blockIdx.y, b = blockIdx.z;
  const int gr = gq & 1, ob = (gq >> 1) * 128;
  const int n0 = nt * 128;
  const int tid = threadIdx.x;
  const int w = tid >> 6, lane = tid & 63, q = lane >> 4, col = lane & 15;
  const unsigned short* yb = (const unsigned short*)(ws + F_Y);

  __shared__ uint4 ldsb[4096];
  char* As = (char*)ldsb;
  char* Bs = (char*)ldsb + 16384;

  f32x4 acc[2][8];
#pragma unroll
  for (int h = 0; h < 2; ++h)
#pragma unroll
    for (int j = 0; j < 8; ++j) acc[h][j] = (f32x4){0.f, 0.f, 0.f, 0.f};

  const int ro = tid >> 1, haf = tid & 1;
  for (int ks = 0; ks < 2; ++ks) {
    __syncthreads();
    {
      const float* src = Ww + (size_t)(ob + ro) * 128 + ks * 64 + haf * 32;
      char* row = As + ro * 128;
      const int sw = (ro & 7) << 4;
#pragma unroll
      for (int jj = 0; jj < 4; ++jj) {
        float4 a = ((const float4*)src)[2 * jj];
        float4 c4 = ((const float4*)src)[2 * jj + 1];
        uint4 pk;
        pk.x = pk2(a.x, a.y);  pk.y = pk2(a.z, a.w);
        pk.z = pk2(c4.x, c4.y); pk.w = pk2(c4.z, c4.w);
        *(uint4*)(row + ((haf * 64 + 16 * jj) ^ sw)) = pk;
      }
    }
    {
      const unsigned short* src = yb + (((size_t)(b * 2 + gr)) * 4096 + n0 + ro) * 128 + ks * 64 + haf * 32;
      char* row = Bs + ro * 128;
      const int sw = (ro & 7) << 4;
#pragma unroll
      for (int jj = 0; jj < 4; ++jj)
        *(uint4*)(row + ((haf * 64 + 16 * jj) ^ sw)) = ((const uint4*)src)[jj];
    }
    __syncthreads();
#pragma unroll
    for (int c = 0; c < 2; ++c) {
      bf16x8 af[2], bfr[8];
#pragma unroll
      for (int h = 0; h < 2; ++h) {
        const int r = 32 * w + 16 * h + col;
        af[h] = *(const bf16x8*)(As + r * 128 + ((64 * c + 16 * q) ^ ((r & 7) << 4)));
      }
#pragma unroll
      for (int j = 0; j < 8; ++j) {
        const int r = 16 * j + col;
        bfr[j] = *(const bf16x8*)(Bs + r * 128 + ((64 * c + 16 * q) ^ ((r & 7) << 4)));
      }
#pragma unroll
      for (int h = 0; h < 2; ++h)
#pragma unroll
        for (int j = 0; j < 8; ++j)
          acc[h][j] = __builtin_amdgcn_mfma_f32_16x16x32_bf16(af[h], bfr[j], acc[h][j], 0, 0, 0);
    }
  }

  __syncthreads();                           // reuse whole LDS: f32 [128 o][512B]
  char* ft = (char*)ldsb;
#pragma unroll
  for (int h = 0; h < 2; ++h) {
    const int o0 = 32 * w + 16 * h + 4 * q;
#pragma unroll
    for (int j = 0; j < 8; ++j) {
      const int n = 16 * j + col;
#pragma unroll
      for (int r = 0; r < 4; ++r)
        *(float*)(ft + (o0 + r) * 512 + ((n * 4) ^ (((o0 + r) & 7) << 4))) = acc[h][j][r];
    }
  }
  __syncthreads();
  {
    const int o = tid >> 1, h2 = tid & 1;
    const float bsv = Wb[ob + o];
    const int ch = 2 * (ob + o) + gr;
    const size_t base = ((size_t)(b * 512 + ch)) * 4096 + n0 + h2 * 64;
    const char* row = ft + o * 512;
    const int sw = (o & 7) << 4;
#pragma unroll
    for (int k = 0; k < 16; ++k) {
      f32x4 v = *(const f32x4*)(row + ((256 * h2 + 16 * k) ^ sw));
      float4 xv = ((const float4*)(x + base))[k];
      ((float4*)(out + base))[k] = make_float4(v[0] + bsv + xv.x, v[1] + bsv + xv.y,
                                               v[2] + bsv + xv.z, v[3] + bsv + xv.w);
    }
  }
}

extern "C" void kernel_launch(void* const* d_in, const int* in_sizes, int n_in,
                              void* d_out, int out_size, void* d_ws, size_t ws_size,
                              hipStream_t stream) {
  const float* x  = (const float*)d_in[0];
  const float* gw = (const float*)d_in[1];
  const float* gb = (const float*)d_in[2];
  const float* tw = (const float*)d_in[3];
  const float* tb = (const float*)d_in[4];
  const float* pw = (const float*)d_in[5];
  const float* pb = (const float*)d_in[6];
  const float* Ww = (const float*)d_in[7];
  const float* Wb = (const float*)d_in[8];
  float* out = (float*)d_out;
  float* ws  = (float*)d_ws;

  k_prep<<<dim3(16, 8, 8), 256, 0, stream>>>(x, ws);
  k_proj_mfma<<<dim3(32, 2, 8), 256, 0, stream>>>(tw, tb, pw, pb, ws);
  k_g_mfma<<<dim3(32, 2, 8), 256, 0, stream>>>(gw, gb, ws);
  k_attn_mfma<<<dim3(8, 64), 256, 0, stream>>>(ws);
  k_final_mfma<<<dim3(32, 4, 8), 256, 0, stream>>>(x, Ww, Wb, ws, out);
}